// Round 10
// baseline (111.804 us; speedup 1.0000x reference)
//
#include <hip/hip_runtime.h>
#include <hip/hip_bf16.h>
#include <stdint.h>

// RadianceNetwork: 256 independent channel MLPs, B=64.
//   x  = concat(ue[3], view[3], feat[128], nid[1])  -> [64, 135]
//   h1 = relu(x @ W1[c] + b1[c])                    -> [64, 256]
//   h2 = relu(h1 @ W2[c] + b2[c])                   -> [64, 256]
//   o  = h2 @ W3[c] + b3[c]                         -> [64, 816]
// OUTPUT: real components only, fp32 [64][256][408] (R0-R5 forensics).
//
// R9 (93us): W staged via LDS dbuf, but prefetch depth 1 -> every k-tile
// exposes ~HBM latency at the stage_write vmcnt (all pipes <10% busy).
// R10: depth-3 REGISTER prefetch. Tile t: regs set t%3, LDS buf t&1.
//   iter kt: issue(kt+3) -> set[kt%3] | sync | compute(kt) | write(kt+1).
// Issue-to-wait distance ~2 full iterations; counted vmcnt leaves 8 loads
// in flight. K-loop fully unrolled so reg-set indexing is static.
// LDS: h1 16K + {x|h2} 16K + Wdbuf 32K = 64 KB -> 2 blocks/CU.
// Grid: 512 blocks = (channel, batch-half), halves paired per XCD.

#define NCH    256
#define BATCH  32     // rows per block (half batch)
#define MT     2      // 16-row m-tiles per block
#define IN_K   135
#define HID    256
#define OUTN   816
#define OUTS   408    // stored real components per (m, c)
#define XPITCHB 336   // bytes per x row (168 bf16; zero-padded k in [135,168))
#define HROWB   512   // bytes per h row (256 bf16, swizzled)
#define NWAVES 8
#define BLOCK  512

typedef __bf16 bf16x8 __attribute__((ext_vector_type(8)));
typedef float  f32x4  __attribute__((ext_vector_type(4)));

// W-tile LDS addressing: k-major rows, row n = 64 B (32 kk x bf16),
// 16B-granular XOR swizzle; reads land at the b128 bank floor.
__device__ __forceinline__ uint32_t wswz(int n, uint32_t kkbyte) {
  return (uint32_t)n * 64u + (kkbyte ^ ((((uint32_t)n >> 2) & 3u) << 4));
}

// Issue coalesced loads for one W k-tile (32 k x NCACT n at nc0).
// Thread t: rows kk0..kk0+3 (kk0 = wave*4), cols c4..c4+3 (c4 = (t&63)*4).
template<int K, int NSRC, int NCACT>
__device__ __forceinline__ void stage_issue(const float* __restrict__ Wg,
                                            int kt, int nc0, int tid, f32x4 ld[4]) {
  const int kk0 = (tid >> 6) * 4;
  const int c4  = (tid & 63) * 4;
  if (c4 < NCACT) {
#pragma unroll
    for (int r = 0; r < 4; ++r) {
      const int k = kt * 32 + kk0 + r;     // uniform per wave -> scalar branch
      if ((K % 32 == 0) || (k < K))
        ld[r] = *(const f32x4*)(Wg + (size_t)k * NSRC + nc0 + c4);
      else
        ld[r] = (f32x4){0.f, 0.f, 0.f, 0.f};
    }
  }
}

// 4x4 in-register transpose -> bf16 -> 4x ds_write_b64 (k-contiguous quads).
template<int NCACT>
__device__ __forceinline__ void stage_write(char* __restrict__ Wb, int tid,
                                            const f32x4 ld[4]) {
  const int kk0 = (tid >> 6) * 4;
  const int c4  = (tid & 63) * 4;
  if (c4 < NCACT) {
#pragma unroll
    for (int j = 0; j < 4; ++j) {
      union { __bf16 h[4]; uint2 u; } pk;
      pk.h[0] = (__bf16)ld[0][j];
      pk.h[1] = (__bf16)ld[1][j];
      pk.h[2] = (__bf16)ld[2][j];
      pk.h[3] = (__bf16)ld[3][j];
      *(uint2*)(Wb + wswz(c4 + j, (uint32_t)(kk0 * 2))) = pk.u;
    }
  }
}

// One N-chunk of one layer: acc over KT k-tiles, depth-3 reg prefetch +
// double-buffered LDS. MFMA 16x16x32 bf16 (layouts HW-verified, m89):
//   A: row m=lane&15, k=(lane>>4)*8+i ; B: col n=lane&15, same k
//   D: col n=lane&15, row m=(lane>>4)*4+r
template<int K, int KT, int NSRC, int NCT, bool ASWZ, bool RELU>
__device__ __forceinline__ void chunk_layer(
    const char*  __restrict__ A,     // LDS activations (x or swizzled h)
    const float* __restrict__ Wg,    // [K][NSRC] weights, channel base
    const float* __restrict__ bg,    // bias, channel base (layer-wide)
    char*        __restrict__ Hout,  // LDS out (RELU), swizzled pitch 512B
    float*       __restrict__ Gout,  // global out base (+c*OUTS)
    unsigned long long out_sz, int nc0,
    char* __restrict__ Wb0, char* __restrict__ Wb1,
    int tid, int wave, int lane, int mbase)
{
  constexpr int NTPW = (NCT + NWAVES - 1) / NWAVES;  // n-tiles per wave
  const int col = lane & 15;
  const int g   = lane >> 4;

  f32x4 acc[NTPW][MT] = {};
  f32x4 ld[3][4];   // depth-3 prefetch: tile t in set t%3

  // prologue: issue 3 tiles, write tile 0 (vmcnt leaves sets 1,2 in flight)
  stage_issue<K, NSRC, NCT * 16>(Wg, 0, nc0, tid, ld[0]);
  if (KT > 1) stage_issue<K, NSRC, NCT * 16>(Wg, 1, nc0, tid, ld[1]);
  if (KT > 2) stage_issue<K, NSRC, NCT * 16>(Wg, 2, nc0, tid, ld[2]);
  stage_write<NCT * 16>(Wb0, tid, ld[0]);

#pragma unroll
  for (int kt = 0; kt < KT; ++kt) {
    char* Wb  = (kt & 1) ? Wb1 : Wb0;
    char* Wbn = (kt & 1) ? Wb0 : Wb1;
    // set[kt%3] held tile kt, already written to LDS -> safe to reload into
    if (kt + 3 < KT) stage_issue<K, NSRC, NCT * 16>(Wg, kt + 3, nc0, tid, ld[kt % 3]);
    __syncthreads();   // staging of Wb(kt) visible to all
    const int kb = kt * 32 + g * 8;
#pragma unroll
    for (int li = 0; li < NTPW; ++li) {
      const int nt = wave + li * NWAVES;
      if ((NCT % NWAVES == 0) || (nt < NCT)) {
        const int nl = nt * 16 + col;
        const bf16x8 bfrag = *(const bf16x8*)(Wb + wswz(nl, (uint32_t)(g * 16)));
#pragma unroll
        for (int mt = 0; mt < MT; ++mt) {
          const int m = mt * 16 + col;
          const uint32_t ab = ASWZ
              ? (uint32_t)m * HROWB + (((uint32_t)(kb * 2)) ^ (((uint32_t)m & 7u) << 4))
              : (uint32_t)m * XPITCHB + (uint32_t)(kb * 2);
          const bf16x8 afrag = *(const bf16x8*)(A + ab);
          acc[li][mt] = __builtin_amdgcn_mfma_f32_16x16x32_bf16(afrag, bfrag, acc[li][mt], 0, 0, 0);
        }
      }
    }
    // write tile kt+1 (loaded 2 iterations ago) into the other buffer;
    // its previous content (tile kt-1) was fully read before this iter's sync
    if (kt + 1 < KT) stage_write<NCT * 16>(Wbn, tid, ld[(kt + 1) % 3]);
  }

  // epilogue: bias (+relu->LDS | even-col fp32->global)
#pragma unroll
  for (int li = 0; li < NTPW; ++li) {
    const int nt = wave + li * NWAVES;
    if ((NCT % NWAVES == 0) || (nt < NCT)) {
      const int n = nc0 + nt * 16 + col;   // layer-wide col
      const float bias = bg[n];
#pragma unroll
      for (int mt = 0; mt < MT; ++mt) {
#pragma unroll
        for (int r = 0; r < 4; ++r) {
          float v = acc[li][mt][r] + bias;
          const int m = mt * 16 + g * 4 + r;   // local row
          if (RELU) {
            v = v > 0.f ? v : 0.f;
            *(__bf16*)(Hout + (uint32_t)m * HROWB +
                       (((uint32_t)((nc0 + nt * 16 + col) * 2)) ^ (((uint32_t)m & 7u) << 4))) = (__bf16)v;
          } else if ((n & 1) == 0) {           // real component only
            const unsigned long long oi =
                (unsigned long long)(mbase + m) * (NCH * OUTS) +
                (unsigned long long)(n >> 1);
            if (oi < out_sz) Gout[oi] = v;
          }
        }
      }
    }
  }
}

__global__ __launch_bounds__(BLOCK) void radiance_mlp_kernel(
    const float* __restrict__ ue,   const float* __restrict__ view,
    const float* __restrict__ feat, const int*   __restrict__ ids,
    const float* __restrict__ W1, const float* __restrict__ b1,
    const float* __restrict__ W2, const float* __restrict__ b2,
    const float* __restrict__ W3, const float* __restrict__ b3,
    float* __restrict__ out, unsigned long long out_sz)
{
  __shared__ __attribute__((aligned(16))) char buf0[BATCH * HROWB];  // h1: 16 KB
  __shared__ __attribute__((aligned(16))) char buf1[BATCH * HROWB];  // x / h2: 16 KB
  __shared__ __attribute__((aligned(16))) char wbuf[2][256 * 64];    // W dbuf: 32 KB

  // blockIdx -> (channel, batch-half); halves paired per XCD (blockIdx%8 rr).
  const int i     = blockIdx.x;
  const int xcd   = i & 7;
  const int j     = i >> 3;
  const int c     = xcd * 32 + (j >> 1);
  const int mbase = (j & 1) * BATCH;

  const int tid  = threadIdx.x;
  const int wave = tid >> 6;
  const int lane = tid & 63;

  // Stage this half's input rows -> bf16 in buf1 (pitch 336B), zero-pad [135,168).
  for (int idx = tid; idx < BATCH * (XPITCHB / 2); idx += BLOCK) {
    const int m  = idx / (XPITCHB / 2);
    const int k  = idx - m * (XPITCHB / 2);
    const int mg = mbase + m;
    float v = 0.0f;
    if (k < 3)         v = ue[mg * 3 + k];
    else if (k < 6)    v = view[mg * 3 + (k - 3)];
    else if (k < 134)  v = feat[mg * 128 + (k - 6)];
    else if (k == 134) v = ((float)ids[mg] - 1.0f) * (1.0f / 63.0f);
    *(__bf16*)(buf1 + (uint32_t)m * XPITCHB + 2u * (uint32_t)k) = (__bf16)v;
  }
  __syncthreads();

  // L1: x(buf1) -> h1(buf0).  K=135 (5 k-tiles, tail predicated), N=256.
  chunk_layer<IN_K, 5, HID, 16, false, true>(
      buf1, W1 + (size_t)c * IN_K * HID, b1 + (size_t)c * HID,
      buf0, nullptr, 0, 0, wbuf[0], wbuf[1], tid, wave, lane, mbase);
  __syncthreads();

  // L2: h1(buf0) -> h2(buf1).  K=256, N=256.
  chunk_layer<HID, 8, HID, 16, true, true>(
      buf0, W2 + (size_t)c * HID * HID, b2 + (size_t)c * HID,
      buf1, nullptr, 0, 0, wbuf[0], wbuf[1], tid, wave, lane, mbase);
  __syncthreads();

  // L3: h2(buf1) -> out.  K=256, N=816 in chunks {256,256,256,48}.
  const float* W3c = W3 + (size_t)c * HID * OUTN;
  const float* b3c = b3 + (size_t)c * OUTN;
  float* outc = out + (size_t)c * OUTS;
  chunk_layer<HID, 8, OUTN, 16, true, false>(
      buf1, W3c, b3c, nullptr, outc, out_sz, 0,   wbuf[0], wbuf[1], tid, wave, lane, mbase);
  __syncthreads();
  chunk_layer<HID, 8, OUTN, 16, true, false>(
      buf1, W3c, b3c, nullptr, outc, out_sz, 256, wbuf[0], wbuf[1], tid, wave, lane, mbase);
  __syncthreads();
  chunk_layer<HID, 8, OUTN, 16, true, false>(
      buf1, W3c, b3c, nullptr, outc, out_sz, 512, wbuf[0], wbuf[1], tid, wave, lane, mbase);
  __syncthreads();
  chunk_layer<HID, 8, OUTN, 3, true, false>(
      buf1, W3c, b3c, nullptr, outc, out_sz, 768, wbuf[0], wbuf[1], tid, wave, lane, mbase);
}

extern "C" void kernel_launch(void* const* d_in, const int* in_sizes, int n_in,
                              void* d_out, int out_size, void* d_ws, size_t ws_size,
                              hipStream_t stream) {
  const float* ue   = (const float*)d_in[0];
  const float* view = (const float*)d_in[1];
  const float* feat = (const float*)d_in[2];
  const int*   ids  = (const int*)d_in[3];
  const float* W1   = (const float*)d_in[4];
  const float* b1   = (const float*)d_in[5];
  const float* W2   = (const float*)d_in[6];
  const float* b2   = (const float*)d_in[7];
  const float* W3   = (const float*)d_in[8];
  const float* b3   = (const float*)d_in[9];
  float* out = (float*)d_out;

  hipLaunchKernelGGL(radiance_mlp_kernel, dim3(NCH * 2), dim3(BLOCK), 0, stream,
                     ue, view, feat, ids, W1, b1, W2, b2, W3, b3,
                     out, (unsigned long long)out_size);
}

// Round 11
// 98.333 us; speedup vs baseline: 1.1370x; 1.1370x over previous
//
#include <hip/hip_runtime.h>
#include <hip/hip_bf16.h>
#include <stdint.h>

// RadianceNetwork: 256 independent channel MLPs, B=64.
//   x  = concat(ue[3], view[3], feat[128], nid[1])  -> [64, 135]
//   h1 = relu(x @ W1[c] + b1[c])                    -> [64, 256]
//   h2 = relu(h1 @ W2[c] + b2[c])                   -> [64, 256]
//   o  = h2 @ W3[c] + b3[c]                         -> [64, 816]
// OUTPUT: real components only, fp32 [64][256][408] (R0-R5 forensics).
//
// R8/R9 (half-batch, 2 blocks/CU) both saturate ~6-7 TB/s DELIVERED bytes
// (636MB: every channel's weights streamed by TWO blocks) while HBM=1.8TB/s
// and all pipes idle -> delivered-BW ceiling, not latency (R10's deeper
// pipeline regressed: depth costs VGPR -> lost 2-blocks/CU co-residency).
// R11: halve delivered bytes. FULL batch per block (grid 256, MT=4), same
// R9 streaming engine (coalesced dwordx4 -> bf16 -> LDS dbuf, issue 1 tile
// ahead). LDS = h1 32K + {x|h2} 32K + Wdbuf 32K = 96KB DYNAMIC (1 block/CU,
// VGPR budget 256/thread -> no co-residency cliff).

#define NCH    256
#define BATCH  64     // full batch per block
#define MT     4      // 16-row m-tiles
#define IN_K   135
#define HID    256
#define OUTN   816
#define OUTS   408    // stored real components per (m, c)
#define XPITCHB 336   // bytes per x row (168 bf16; zero-padded k in [135,168))
#define HROWB   512   // bytes per h row (256 bf16, swizzled)
#define NWAVES 8
#define BLOCK  512
#define SMEM_BYTES (96 * 1024)

typedef __bf16 bf16x8 __attribute__((ext_vector_type(8)));
typedef float  f32x4  __attribute__((ext_vector_type(4)));

// W-tile LDS addressing: k-major rows, row n = 64 B (32 kk x bf16),
// 16B-granular XOR swizzle; reads land at the b128 bank floor.
__device__ __forceinline__ uint32_t wswz(int n, uint32_t kkbyte) {
  return (uint32_t)n * 64u + (kkbyte ^ ((((uint32_t)n >> 2) & 3u) << 4));
}

// Issue coalesced loads for one W k-tile (32 k x NCACT n at nc0).
// Thread t: rows kk0..kk0+3 (kk0 = wave*4), cols c4..c4+3 (c4 = (t&63)*4).
template<int K, int NSRC, int NCACT>
__device__ __forceinline__ void stage_issue(const float* __restrict__ Wg,
                                            int kt, int nc0, int tid, f32x4 ld[4]) {
  const int kk0 = (tid >> 6) * 4;
  const int c4  = (tid & 63) * 4;
  if (c4 < NCACT) {
#pragma unroll
    for (int r = 0; r < 4; ++r) {
      const int k = kt * 32 + kk0 + r;     // uniform per wave -> scalar branch
      if ((K % 32 == 0) || (k < K))
        ld[r] = *(const f32x4*)(Wg + (size_t)k * NSRC + nc0 + c4);
      else
        ld[r] = (f32x4){0.f, 0.f, 0.f, 0.f};
    }
  }
}

// 4x4 in-register transpose -> bf16 -> 4x ds_write_b64 (k-contiguous quads).
template<int NCACT>
__device__ __forceinline__ void stage_write(char* __restrict__ Wb, int tid,
                                            const f32x4 ld[4]) {
  const int kk0 = (tid >> 6) * 4;
  const int c4  = (tid & 63) * 4;
  if (c4 < NCACT) {
#pragma unroll
    for (int j = 0; j < 4; ++j) {
      union { __bf16 h[4]; uint2 u; } pk;
      pk.h[0] = (__bf16)ld[0][j];
      pk.h[1] = (__bf16)ld[1][j];
      pk.h[2] = (__bf16)ld[2][j];
      pk.h[3] = (__bf16)ld[3][j];
      *(uint2*)(Wb + wswz(c4 + j, (uint32_t)(kk0 * 2))) = pk.u;
    }
  }
}

// One N-chunk of one layer: acc over KT k-tiles with double-buffered W
// staging, loads issued one tile ahead. MFMA 16x16x32 bf16 (m89 layouts):
//   A: row m=lane&15, k=(lane>>4)*8+i ; B: col n=lane&15, same k
//   D: col n=lane&15, row m=(lane>>4)*4+r
template<int K, int KT, int NSRC, int NCT, bool ASWZ, bool RELU>
__device__ __forceinline__ void chunk_layer(
    const char*  __restrict__ A,     // LDS activations (x or swizzled h)
    const float* __restrict__ Wg,    // [K][NSRC] weights, channel base
    const float* __restrict__ bg,    // bias, channel base (layer-wide)
    char*        __restrict__ Hout,  // LDS out (RELU), swizzled pitch 512B
    float*       __restrict__ Gout,  // global out base (+c*OUTS)
    unsigned long long out_sz, int nc0,
    char* __restrict__ Wb0, char* __restrict__ Wb1,
    int tid, int wave, int lane)
{
  constexpr int NTPW = (NCT + NWAVES - 1) / NWAVES;  // n-tiles per wave
  const int col = lane & 15;
  const int g   = lane >> 4;

  f32x4 acc[NTPW][MT] = {};
  f32x4 ld[4];

  // prologue: stage k-tile 0 (latency exposed once per chunk)
  stage_issue<K, NSRC, NCT * 16>(Wg, 0, nc0, tid, ld);
  stage_write<NCT * 16>(Wb0, tid, ld);

#pragma unroll
  for (int kt = 0; kt < KT; ++kt) {
    char* Wb  = (kt & 1) ? Wb1 : Wb0;
    char* Wbn = (kt & 1) ? Wb0 : Wb1;
    const bool more = (kt + 1 < KT);
    if (more) stage_issue<K, NSRC, NCT * 16>(Wg, kt + 1, nc0, tid, ld);  // in flight across compute
    __syncthreads();   // staging of Wb(kt) visible to all
    const int kb = kt * 32 + g * 8;
#pragma unroll
    for (int li = 0; li < NTPW; ++li) {
      const int nt = wave + li * NWAVES;
      if ((NCT % NWAVES == 0) || (nt < NCT)) {
        const int nl = nt * 16 + col;
        const bf16x8 bfrag = *(const bf16x8*)(Wb + wswz(nl, (uint32_t)(g * 16)));
#pragma unroll
        for (int mt = 0; mt < MT; ++mt) {
          const int m = mt * 16 + col;
          const uint32_t ab = ASWZ
              ? (uint32_t)m * HROWB + (((uint32_t)(kb * 2)) ^ (((uint32_t)m & 7u) << 4))
              : (uint32_t)m * XPITCHB + (uint32_t)(kb * 2);
          const bf16x8 afrag = *(const bf16x8*)(A + ab);
          acc[li][mt] = __builtin_amdgcn_mfma_f32_16x16x32_bf16(afrag, bfrag, acc[li][mt], 0, 0, 0);
        }
      }
    }
    if (more) stage_write<NCT * 16>(Wbn, tid, ld);  // other buffer; next BAR orders reads
  }

  // epilogue: bias (+relu->LDS | even-col fp32->global)
#pragma unroll
  for (int li = 0; li < NTPW; ++li) {
    const int nt = wave + li * NWAVES;
    if ((NCT % NWAVES == 0) || (nt < NCT)) {
      const int n = nc0 + nt * 16 + col;   // layer-wide col
      const float bias = bg[n];
#pragma unroll
      for (int mt = 0; mt < MT; ++mt) {
#pragma unroll
        for (int r = 0; r < 4; ++r) {
          float v = acc[li][mt][r] + bias;
          const int m = mt * 16 + g * 4 + r;
          if (RELU) {
            v = v > 0.f ? v : 0.f;
            *(__bf16*)(Hout + (uint32_t)m * HROWB +
                       (((uint32_t)(n * 2)) ^ (((uint32_t)m & 7u) << 4))) = (__bf16)v;
          } else if ((n & 1) == 0) {           // real component only
            const unsigned long long oi =
                (unsigned long long)m * (NCH * OUTS) + (unsigned long long)(n >> 1);
            if (oi < out_sz) Gout[oi] = v;
          }
        }
      }
    }
  }
}

__global__ __launch_bounds__(BLOCK) void radiance_mlp_kernel(
    const float* __restrict__ ue,   const float* __restrict__ view,
    const float* __restrict__ feat, const int*   __restrict__ ids,
    const float* __restrict__ W1, const float* __restrict__ b1,
    const float* __restrict__ W2, const float* __restrict__ b2,
    const float* __restrict__ W3, const float* __restrict__ b3,
    float* __restrict__ out, unsigned long long out_sz)
{
  extern __shared__ __attribute__((aligned(16))) char smem[];
  char* buf0 = smem;                 // h1: 32 KB (swizzled pitch 512B)
  char* buf1 = smem + 32768;         // x (pitch 336B) then h2: 32 KB
  char* wb0  = smem + 65536;         // W tile A: 16 KB
  char* wb1  = smem + 81920;         // W tile B: 16 KB

  const int c    = blockIdx.x;       // one full-batch block per channel
  const int tid  = threadIdx.x;
  const int wave = tid >> 6;
  const int lane = tid & 63;

  // Stage input x -> bf16 in buf1 (pitch 336B), zero-pad k in [135,168).
  for (int idx = tid; idx < BATCH * (XPITCHB / 2); idx += BLOCK) {
    const int m = idx / (XPITCHB / 2);
    const int k = idx - m * (XPITCHB / 2);
    float v = 0.0f;
    if (k < 3)         v = ue[m * 3 + k];
    else if (k < 6)    v = view[m * 3 + (k - 3)];
    else if (k < 134)  v = feat[m * 128 + (k - 6)];
    else if (k == 134) v = ((float)ids[m] - 1.0f) * (1.0f / 63.0f);
    *(__bf16*)(buf1 + (uint32_t)m * XPITCHB + 2u * (uint32_t)k) = (__bf16)v;
  }
  __syncthreads();

  // L1: x(buf1) -> h1(buf0).  K=135 (5 k-tiles, tail predicated), N=256.
  chunk_layer<IN_K, 5, HID, 16, false, true>(
      buf1, W1 + (size_t)c * IN_K * HID, b1 + (size_t)c * HID,
      buf0, nullptr, 0, 0, wb0, wb1, tid, wave, lane);
  __syncthreads();

  // L2: h1(buf0) -> h2(buf1).  K=256, N=256.
  chunk_layer<HID, 8, HID, 16, true, true>(
      buf0, W2 + (size_t)c * HID * HID, b2 + (size_t)c * HID,
      buf1, nullptr, 0, 0, wb0, wb1, tid, wave, lane);
  __syncthreads();

  // L3: h2(buf1) -> out.  K=256, N=816 in chunks {256,256,256,48}.
  const float* W3c = W3 + (size_t)c * HID * OUTN;
  const float* b3c = b3 + (size_t)c * OUTN;
  float* outc = out + (size_t)c * OUTS;
  chunk_layer<HID, 8, OUTN, 16, true, false>(
      buf1, W3c, b3c, nullptr, outc, out_sz, 0,   wb0, wb1, tid, wave, lane);
  __syncthreads();
  chunk_layer<HID, 8, OUTN, 16, true, false>(
      buf1, W3c, b3c, nullptr, outc, out_sz, 256, wb0, wb1, tid, wave, lane);
  __syncthreads();
  chunk_layer<HID, 8, OUTN, 16, true, false>(
      buf1, W3c, b3c, nullptr, outc, out_sz, 512, wb0, wb1, tid, wave, lane);
  __syncthreads();
  chunk_layer<HID, 8, OUTN, 3, true, false>(
      buf1, W3c, b3c, nullptr, outc, out_sz, 768, wb0, wb1, tid, wave, lane);
}

extern "C" void kernel_launch(void* const* d_in, const int* in_sizes, int n_in,
                              void* d_out, int out_size, void* d_ws, size_t ws_size,
                              hipStream_t stream) {
  const float* ue   = (const float*)d_in[0];
  const float* view = (const float*)d_in[1];
  const float* feat = (const float*)d_in[2];
  const int*   ids  = (const int*)d_in[3];
  const float* W1   = (const float*)d_in[4];
  const float* b1   = (const float*)d_in[5];
  const float* W2   = (const float*)d_in[6];
  const float* b2   = (const float*)d_in[7];
  const float* W3   = (const float*)d_in[8];
  const float* b3   = (const float*)d_in[9];
  float* out = (float*)d_out;

  // Host-side attribute set (not a stream op; graph-capture-safe, idempotent).
  hipFuncSetAttribute(reinterpret_cast<const void*>(radiance_mlp_kernel),
                      hipFuncAttributeMaxDynamicSharedMemorySize, SMEM_BYTES);

  hipLaunchKernelGGL(radiance_mlp_kernel, dim3(NCH), dim3(BLOCK), SMEM_BYTES,
                     stream, ue, view, feat, ids, W1, b1, W2, b2, W3, b3,
                     out, (unsigned long long)out_size);
}

// Round 12
// 93.881 us; speedup vs baseline: 1.1909x; 1.0474x over previous
//
#include <hip/hip_runtime.h>
#include <hip/hip_bf16.h>
#include <stdint.h>

// RadianceNetwork: 256 independent channel MLPs, B=64.
//   x  = concat(ue[3], view[3], feat[128], nid[1])  -> [64, 135]
//   h1 = relu(x @ W1[c] + b1[c])                    -> [64, 256]
//   h2 = relu(h1 @ W2[c] + b2[c])                   -> [64, 256]
//   o  = h2 @ W3[c] + b3[c]                         -> [64, 816]
// OUTPUT: real components only, fp32 [64][256][408] (R0-R5 forensics).
//
// R9/R11 lesson: hipcc drains vmcnt(0) before EVERY s_barrier, so the
// per-k-tile __syncthreads of block-wide W staging exposes full memory
// latency ~45x per block; all pipes <10% busy. R12 removes the barriers:
// WAVE-PRIVATE W staging. Each wave stages its own 32kx16n tile into its
// own 2KB LDS dbuf slot (coalesced dwordx4 -> bf16 -> 4x ds_write_b32,
// k-major XOR-swizzled rows; B-frag = one ds_read_b128). Depth-2 load
// lookahead (3 reg sets, static unroll). NO barriers inside layers; 4 seam
// barriers total. Waves stall independently -> latencies overlap.
// LDS: h1 32K + {x|h2} 32K + wstage 16K = 80KB dynamic. Grid 256, BLOCK 512.

#define NCH    256
#define BATCH  64
#define MT     4      // 16-row m-tiles (full batch)
#define IN_K   135
#define HID    256
#define OUTN   816
#define OUTS   408    // stored real components per (m, c)
#define XPITCHB 336   // bytes per x row (168 bf16; zero-padded k in [135,168))
#define HROWB   512   // bytes per h row (256 bf16, swizzled)
#define NWAVES 8
#define BLOCK  512
#define SMEM_BYTES (80 * 1024)

typedef __bf16 bf16x8 __attribute__((ext_vector_type(8)));
typedef float  f32x4  __attribute__((ext_vector_type(4)));

// One layer, barrier-free. MFMA 16x16x32 bf16 (layouts HW-verified, m89):
//   A: row m=lane&15, k=(lane>>4)*8+i  (ds_read_b128 from shared h/x LDS)
//   B: col n=lane&15, k=(lane>>4)*8+i  (ds_read_b128 from wave-private tile)
//   D: col n=lane&15, row m=(lane>>4)*4+r
// Wave-private W tile: k-major rows, row n = 64B (32 k x bf16),
// byte(n,k) = n*64 + (k*2 ^ (((n>>2)&3)<<4)); conflict-free b128 reads,
// ~4-way (free-ish) b32 staging writes.
template<int K, int KT, int NSRC, int NTT, bool ASWZ, bool RELU>
__device__ __forceinline__ void layer_nobar(
    const char*  __restrict__ A,     // LDS activations (x or swizzled h)
    const float* __restrict__ Wg,    // [K][NSRC] weights, channel base
    const float* __restrict__ bg,    // bias, channel base
    char*        __restrict__ Hout,  // LDS out (RELU), swizzled pitch 512B
    float*       __restrict__ Gout,  // global out base (+c*OUTS)
    unsigned long long out_sz,
    char* __restrict__ Wb,           // wave-private 2048B (2 x 1KB)
    int wave, int lane)
{
  const int col = lane & 15;
  const int g   = lane >> 4;
  const int d   = lane >> 2;        // 0..15: k-pair row within tile
  const int q   = lane & 3;         // col quad

  for (int nt = wave; nt < NTT; nt += NWAVES) {
    const int nb = nt * 16;
    f32x4 ld[3][2];                 // depth-2 lookahead: tile t in set t%3
    f32x4 acc[MT] = {};

    // --- staging helpers (wave-local; compiler counts vmcnt/lgkmcnt) ---
    auto issue = [&](int s, int kt) {
#pragma unroll
      for (int h = 0; h < 2; ++h) {
        const int k = kt * 32 + 2 * d + h;
        if ((K % 32 == 0) || (k < K))
          ld[s][h] = *(const f32x4*)(Wg + (size_t)k * NSRC + nb + q * 4);
        else
          ld[s][h] = (f32x4){0.f, 0.f, 0.f, 0.f};  // K tail: A is zero-padded
      }
    };
    auto wwrite = [&](int buf, int s) {
      char* W = Wb + buf * 1024;
#pragma unroll
      for (int j = 0; j < 4; ++j) {
        const int n = q * 4 + j;
        union { __bf16 b[2]; uint32_t u; } pk;
        pk.b[0] = (__bf16)ld[s][0][j];   // k = 2d   (low)
        pk.b[1] = (__bf16)ld[s][1][j];   // k = 2d+1 (high)
        *(uint32_t*)(W + (uint32_t)n * 64u +
                     (((uint32_t)(4 * d)) ^ ((((uint32_t)n >> 2) & 3u) << 4))) = pk.u;
      }
    };

    // prologue: tiles 0,1 in flight; tile 0 into LDS
    issue(0, 0);
    if (KT > 1) issue(1, 1);
    wwrite(0, 0);

#pragma unroll
    for (int kt = 0; kt < KT; ++kt) {
      if (kt + 2 < KT) issue((kt + 2) % 3, kt + 2);      // keep 2 tiles in flight
      if (kt + 1 < KT) wwrite((kt + 1) & 1, (kt + 1) % 3); // other LDS half
      // compute tile kt from LDS half kt&1
      const char* W = Wb + (kt & 1) * 1024;
      const bf16x8 bfrag = *(const bf16x8*)(W + (uint32_t)col * 64u +
          (((uint32_t)(16 * g)) ^ ((((uint32_t)col >> 2) & 3u) << 4)));
      const int kb = kt * 32 + g * 8;
#pragma unroll
      for (int mt = 0; mt < MT; ++mt) {
        const int m = mt * 16 + col;
        const uint32_t ab = ASWZ
            ? (uint32_t)m * HROWB + (((uint32_t)(kb * 2)) ^ (((uint32_t)m & 7u) << 4))
            : (uint32_t)m * XPITCHB + (uint32_t)(kb * 2);
        const bf16x8 afrag = *(const bf16x8*)(A + ab);
        acc[mt] = __builtin_amdgcn_mfma_f32_16x16x32_bf16(afrag, bfrag, acc[mt], 0, 0, 0);
      }
    }

    // epilogue: bias (+relu->LDS | even-col fp32->global)
    const float bias = bg[nb + col];
#pragma unroll
    for (int mt = 0; mt < MT; ++mt) {
#pragma unroll
      for (int r = 0; r < 4; ++r) {
        float v = acc[mt][r] + bias;
        const int m = mt * 16 + g * 4 + r;
        const int n = nb + col;
        if (RELU) {
          v = v > 0.f ? v : 0.f;
          *(__bf16*)(Hout + (uint32_t)m * HROWB +
                     (((uint32_t)(n * 2)) ^ (((uint32_t)m & 7u) << 4))) = (__bf16)v;
        } else if ((n & 1) == 0) {           // real component only
          const unsigned long long oi =
              (unsigned long long)m * (NCH * OUTS) + (unsigned long long)(n >> 1);
          if (oi < out_sz) Gout[oi] = v;
        }
      }
    }
  }
}

__global__ __launch_bounds__(BLOCK) void radiance_mlp_kernel(
    const float* __restrict__ ue,   const float* __restrict__ view,
    const float* __restrict__ feat, const int*   __restrict__ ids,
    const float* __restrict__ W1, const float* __restrict__ b1,
    const float* __restrict__ W2, const float* __restrict__ b2,
    const float* __restrict__ W3, const float* __restrict__ b3,
    float* __restrict__ out, unsigned long long out_sz)
{
  extern __shared__ __attribute__((aligned(16))) char smem[];
  char* buf0  = smem;                 // h1: 32 KB (swizzled pitch 512B)
  char* buf1  = smem + 32768;         // x (pitch 336B) then h2: 32 KB
  char* wbase = smem + 65536;         // 8 waves x 2KB private W dbuf: 16 KB

  const int c    = blockIdx.x;        // one full-batch block per channel
  const int tid  = threadIdx.x;
  const int wave = tid >> 6;
  const int lane = tid & 63;
  char* myWb = wbase + wave * 2048;

  // Stage input x -> bf16 in buf1 (pitch 336B), zero-pad k in [135,168).
  for (int idx = tid; idx < BATCH * (XPITCHB / 2); idx += BLOCK) {
    const int m = idx / (XPITCHB / 2);
    const int k = idx - m * (XPITCHB / 2);
    float v = 0.0f;
    if (k < 3)         v = ue[m * 3 + k];
    else if (k < 6)    v = view[m * 3 + (k - 3)];
    else if (k < 134)  v = feat[m * 128 + (k - 6)];
    else if (k == 134) v = ((float)ids[m] - 1.0f) * (1.0f / 63.0f);
    *(__bf16*)(buf1 + (uint32_t)m * XPITCHB + 2u * (uint32_t)k) = (__bf16)v;
  }
  __syncthreads();

  // L1: x(buf1) -> h1(buf0).  K=135 (5 k-tiles, tail predicated), N=256.
  layer_nobar<IN_K, 5, HID, 16, false, true>(
      buf1, W1 + (size_t)c * IN_K * HID, b1 + (size_t)c * HID,
      buf0, nullptr, 0, myWb, wave, lane);
  __syncthreads();

  // L2: h1(buf0) -> h2(buf1).  K=256, N=256.
  layer_nobar<HID, 8, HID, 16, true, true>(
      buf0, W2 + (size_t)c * HID * HID, b2 + (size_t)c * HID,
      buf1, nullptr, 0, myWb, wave, lane);
  __syncthreads();

  // L3: h2(buf1) -> out.  K=256, N=816 (51 n-tiles round-robin over waves).
  layer_nobar<HID, 8, OUTN, 51, true, false>(
      buf1, W3 + (size_t)c * HID * OUTN, b3 + (size_t)c * OUTN,
      nullptr, out + (size_t)c * OUTS, out_sz, myWb, wave, lane);
}

extern "C" void kernel_launch(void* const* d_in, const int* in_sizes, int n_in,
                              void* d_out, int out_size, void* d_ws, size_t ws_size,
                              hipStream_t stream) {
  const float* ue   = (const float*)d_in[0];
  const float* view = (const float*)d_in[1];
  const float* feat = (const float*)d_in[2];
  const int*   ids  = (const int*)d_in[3];
  const float* W1   = (const float*)d_in[4];
  const float* b1   = (const float*)d_in[5];
  const float* W2   = (const float*)d_in[6];
  const float* b2   = (const float*)d_in[7];
  const float* W3   = (const float*)d_in[8];
  const float* b3   = (const float*)d_in[9];
  float* out = (float*)d_out;

  // Host-side attribute set (not a stream op; graph-capture-safe, idempotent).
  hipFuncSetAttribute(reinterpret_cast<const void*>(radiance_mlp_kernel),
                      hipFuncAttributeMaxDynamicSharedMemorySize, SMEM_BYTES);

  hipLaunchKernelGGL(radiance_mlp_kernel, dim3(NCH), dim3(BLOCK), SMEM_BYTES,
                     stream, ue, view, feat, ids, W1, b1, W2, b2, W3, b3,
                     out, (unsigned long long)out_size);
}